// Round 4
// baseline (321.155 us; speedup 1.0000x reference)
//
#include <hip/hip_runtime.h>

#define CLAMP_THR 0.9999999f

typedef float f4 __attribute__((ext_vector_type(4)));

constexpr int ELEMS = 256;        // elements per chunk == blockDim.x
constexpr int FLTS  = ELEMS * 9;  // 2304 floats per array per chunk
constexpr int VEC   = FLTS / 4;   // 576 float4 per array per chunk

__global__ void zero_loss_kernel(float* out) {
    if (threadIdx.x == 0) out[0] = 0.0f;
}

// Store one chunk (FLTS floats) from LDS to a 4B-aligned (but not necessarily
// 16B-aligned) global destination using aligned float4 stores for the interior
// and scalar stores for the <=3 head / <=3 tail floats.
__device__ inline void store_chunk(float* __restrict__ dst,
                                   const float* __restrict__ src, int t)
{
    const int i0 = (int)(((16u - ((uintptr_t)dst & 15u)) & 15u) >> 2); // 0..3
    const int nv = (FLTS - i0) / 4;
    f4* __restrict__ v = (f4*)(dst + i0);
    for (int i = t; i < nv; i += 256) {
        const int s = 4 * i + i0;
        f4 x = { src[s], src[s + 1], src[s + 2], src[s + 3] };
        __builtin_nontemporal_store(x, v + i);
    }
    if (t < i0) dst[t] = src[t];                 // head floats
    const int tb = i0 + 4 * nv;                  // tail begin
    const int ntail = FLTS - tb;                 // 0..3
    if (t >= 4 && t < 4 + ntail) {
        const int i = tb + (t - 4);
        dst[i] = src[i];
    }
}

__global__ __launch_bounds__(256) void geodesic_grad_kernel(
    const float* __restrict__ Rrel,   // [N,3,3]
    const float* __restrict__ Rw1,    // [N,3,3]  (R_w2c1)
    const float* __restrict__ Rw2,    // [N,3,3]  (R_w2c2)
    float* __restrict__ out,          // [1 + 9N + 9N]
    int n)
{
    __shared__ float lA[FLTS];  // stages R_rel,  then d_R_w2c1
    __shared__ float lB[FLTS];  // stages R_w2c2, then d_R_w2c2
    __shared__ float lC[FLTS];  // stages R_w2c1
    __shared__ float wsum[4];

    const int t = threadIdx.x;
    const int c = blockIdx.x;
    const size_t base = (size_t)c * FLTS;
    const int valid = min(ELEMS, n - c * ELEMS);
    const int vf = valid * 9;

    float* __restrict__ out1 = out + 1;                    // d_R_w2c1
    float* __restrict__ out2 = out + 1 + (size_t)n * 9;    // d_R_w2c2

    // ---- global -> LDS staging (aligned float4, coalesced) ----
    if (valid == ELEMS) {
        const f4* __restrict__ gA = (const f4*)(Rrel + base);
        const f4* __restrict__ gB = (const f4*)(Rw2 + base);
        const f4* __restrict__ gC = (const f4*)(Rw1 + base);
        f4* __restrict__ sA = (f4*)lA;
        f4* __restrict__ sB = (f4*)lB;
        f4* __restrict__ sC = (f4*)lC;
        #pragma unroll
        for (int i = t; i < VEC; i += 256) {
            sA[i] = gA[i];
            sB[i] = gB[i];
            sC[i] = gC[i];
        }
    } else {
        for (int i = t; i < vf; i += 256) {
            lA[i] = Rrel[base + i];
            lB[i] = Rw2[base + i];
            lC[i] = Rw1[base + i];
        }
    }
    __syncthreads();

    // ---- per-element compute (thread t owns LDS slots [9t, 9t+9)) ----
    float local_loss = 0.0f;
    if (t < valid) {
        float R[9], A[9], B[9];
        #pragma unroll
        for (int j = 0; j < 9; ++j) {
            R[j] = lA[9 * t + j];   // R_rel
            A[j] = lB[9 * t + j];   // R_w2c2
            B[j] = lC[9 * t + j];   // R_w2c1
        }
        // M = R_rel^T @ R_w2c2 ; M[i][k] = sum_j R[j][i]*A[j][k]
        float M[9];
        #pragma unroll
        for (int i = 0; i < 3; ++i)
            #pragma unroll
            for (int k = 0; k < 3; ++k)
                M[3 * i + k] = R[i]     * A[k]
                             + R[3 + i] * A[3 + k]
                             + R[6 + i] * A[6 + k];
        float tr = 0.0f;
        #pragma unroll
        for (int j = 0; j < 9; ++j) tr += M[j] * B[j];

        float cosv = 0.5f * (tr - 1.0f);
        float cosc = fminf(fmaxf(cosv, -CLAMP_THR), CLAMP_THR);
        local_loss = acosf(cosc);
        float g = (fabsf(cosv) < CLAMP_THR)
                    ? (-0.5f / sqrtf(1.0f - cosc * cosc))
                    : 0.0f;

        // d_R_w2c1 = g * M  -> lA (own slot)
        #pragma unroll
        for (int j = 0; j < 9; ++j) lA[9 * t + j] = g * M[j];
        // d_R_w2c2 = g * (R_rel @ R_w2c1) -> lB
        #pragma unroll
        for (int i = 0; i < 3; ++i)
            #pragma unroll
            for (int k = 0; k < 3; ++k)
                lB[9 * t + 3 * i + k] = g * (R[3 * i]     * B[k]
                                           + R[3 * i + 1] * B[3 + k]
                                           + R[3 * i + 2] * B[6 + k]);
    }
    __syncthreads();

    // ---- LDS -> global stores (aligned float4 interior + scalar edges) ----
    if (valid == ELEMS) {
        store_chunk(out1 + base, lA, t);
        store_chunk(out2 + base, lB, t);
    } else {
        for (int i = t; i < vf; i += 256) {
            out1[base + i] = lA[i];
            out2[base + i] = lB[i];
        }
    }

    // ---- loss reduction: wave shuffle -> block -> one atomic per block ----
    #pragma unroll
    for (int off = 32; off > 0; off >>= 1)
        local_loss += __shfl_down(local_loss, off, 64);
    if ((t & 63) == 0) wsum[t >> 6] = local_loss;
    __syncthreads();
    if (t == 0)
        atomicAdd(out, wsum[0] + wsum[1] + wsum[2] + wsum[3]);
}

extern "C" void kernel_launch(void* const* d_in, const int* in_sizes, int n_in,
                              void* d_out, int out_size, void* d_ws, size_t ws_size,
                              hipStream_t stream) {
    const float* Rrel = (const float*)d_in[0];
    const float* Rw1  = (const float*)d_in[1];
    const float* Rw2  = (const float*)d_in[2];
    float* out = (float*)d_out;
    const int n = in_sizes[0] / 9;

    zero_loss_kernel<<<1, 64, 0, stream>>>(out);

    const int nChunks = (n + ELEMS - 1) / ELEMS;
    geodesic_grad_kernel<<<nChunks, 256, 0, stream>>>(Rrel, Rw1, Rw2, out, n);
}

// Round 6
// 299.320 us; speedup vs baseline: 1.0729x; 1.0729x over previous
//
#include <hip/hip_runtime.h>

#define CLAMP_THR 0.9999999f

// 4-byte-aligned float4: element base (9*e floats) is only dword-aligned.
typedef float f4a __attribute__((ext_vector_type(4), aligned(4)));

__global__ void zero_loss_kernel(float* out) {
    if (threadIdx.x == 0) out[0] = 0.0f;
}

template<bool USE_WS>
__global__ __launch_bounds__(256) void geodesic_direct_kernel(
    const float* __restrict__ Rrel,   // [N,3,3]
    const float* __restrict__ Rw1,    // [N,3,3]  R_w2c1
    const float* __restrict__ Rw2,    // [N,3,3]  R_w2c2
    float* __restrict__ out,          // [1 + 9N + 9N]
    float* __restrict__ ws,           // per-block loss partials (USE_WS)
    int n)
{
    __shared__ float wsum[4];
    const int t = threadIdx.x;
    const int e = blockIdx.x * 256 + t;

    float local_loss = 0.0f;
    if (e < n) {
        const size_t b = (size_t)e * 9;
        float R[9], A[9], B[9];

        f4a v;
        v = *(const f4a*)(Rrel + b);     R[0]=v.x; R[1]=v.y; R[2]=v.z; R[3]=v.w;
        v = *(const f4a*)(Rrel + b + 4); R[4]=v.x; R[5]=v.y; R[6]=v.z; R[7]=v.w;
        R[8] = Rrel[b + 8];
        v = *(const f4a*)(Rw2 + b);      A[0]=v.x; A[1]=v.y; A[2]=v.z; A[3]=v.w;
        v = *(const f4a*)(Rw2 + b + 4);  A[4]=v.x; A[5]=v.y; A[6]=v.z; A[7]=v.w;
        A[8] = Rw2[b + 8];
        v = *(const f4a*)(Rw1 + b);      B[0]=v.x; B[1]=v.y; B[2]=v.z; B[3]=v.w;
        v = *(const f4a*)(Rw1 + b + 4);  B[4]=v.x; B[5]=v.y; B[6]=v.z; B[7]=v.w;
        B[8] = Rw1[b + 8];

        // M = R_rel^T @ R_w2c2 ; M[i][k] = sum_j R[j][i]*A[j][k]
        float M[9];
        #pragma unroll
        for (int i = 0; i < 3; ++i)
            #pragma unroll
            for (int k = 0; k < 3; ++k)
                M[3 * i + k] = R[i]     * A[k]
                             + R[3 + i] * A[3 + k]
                             + R[6 + i] * A[6 + k];
        float tr = 0.0f;
        #pragma unroll
        for (int j = 0; j < 9; ++j) tr += M[j] * B[j];

        float cosv = 0.5f * (tr - 1.0f);
        float cosc = fminf(fmaxf(cosv, -CLAMP_THR), CLAMP_THR);
        local_loss = acosf(cosc);
        float g = (fabsf(cosv) < CLAMP_THR)
                    ? (-0.5f / sqrtf(1.0f - cosc * cosc))
                    : 0.0f;

        // d_R_w2c1 = g * M
        float* __restrict__ o1 = out + 1 + b;
        f4a s;
        s.x = g*M[0]; s.y = g*M[1]; s.z = g*M[2]; s.w = g*M[3];
        *(f4a*)(o1) = s;
        s.x = g*M[4]; s.y = g*M[5]; s.z = g*M[6]; s.w = g*M[7];
        *(f4a*)(o1 + 4) = s;
        o1[8] = g*M[8];

        // d_R_w2c2 = g * (R_rel @ R_w2c1); [i][k] = sum_j R[i][j]*B[j][k]
        float D[9];
        #pragma unroll
        for (int i = 0; i < 3; ++i)
            #pragma unroll
            for (int k = 0; k < 3; ++k)
                D[3 * i + k] = g * (R[3 * i]     * B[k]
                                  + R[3 * i + 1] * B[3 + k]
                                  + R[3 * i + 2] * B[6 + k]);
        float* __restrict__ o2 = out + 1 + (size_t)n * 9 + b;
        s.x = D[0]; s.y = D[1]; s.z = D[2]; s.w = D[3];
        *(f4a*)(o2) = s;
        s.x = D[4]; s.y = D[5]; s.z = D[6]; s.w = D[7];
        *(f4a*)(o2 + 4) = s;
        o2[8] = D[8];
    }

    // ---- loss reduction: wave shuffle -> block partial ----
    #pragma unroll
    for (int off = 32; off > 0; off >>= 1)
        local_loss += __shfl_down(local_loss, off, 64);
    if ((t & 63) == 0) wsum[t >> 6] = local_loss;
    __syncthreads();
    if (t == 0) {
        const float blocksum = wsum[0] + wsum[1] + wsum[2] + wsum[3];
        if (USE_WS) ws[blockIdx.x] = blocksum;
        else        atomicAdd(out, blocksum);
    }
}

__global__ __launch_bounds__(1024) void reduce_loss_kernel(
    const float* __restrict__ ws, int nb, float* __restrict__ out)
{
    __shared__ float wsum[16];
    const int t = threadIdx.x;
    float s = 0.0f;
    for (int i = t; i < nb; i += 1024) s += ws[i];
    #pragma unroll
    for (int off = 32; off > 0; off >>= 1)
        s += __shfl_down(s, off, 64);
    if ((t & 63) == 0) wsum[t >> 6] = s;
    __syncthreads();
    if (t == 0) {
        float tot = 0.0f;
        #pragma unroll
        for (int i = 0; i < 16; ++i) tot += wsum[i];
        out[0] = tot;
    }
}

extern "C" void kernel_launch(void* const* d_in, const int* in_sizes, int n_in,
                              void* d_out, int out_size, void* d_ws, size_t ws_size,
                              hipStream_t stream) {
    const float* Rrel = (const float*)d_in[0];
    const float* Rw1  = (const float*)d_in[1];
    const float* Rw2  = (const float*)d_in[2];
    float* out = (float*)d_out;
    const int n = in_sizes[0] / 9;
    const int nb = (n + 255) / 256;

    if (ws_size >= (size_t)nb * sizeof(float)) {
        geodesic_direct_kernel<true><<<nb, 256, 0, stream>>>(
            Rrel, Rw1, Rw2, out, (float*)d_ws, n);
        reduce_loss_kernel<<<1, 1024, 0, stream>>>((const float*)d_ws, nb, out);
    } else {
        zero_loss_kernel<<<1, 64, 0, stream>>>(out);
        geodesic_direct_kernel<false><<<nb, 256, 0, stream>>>(
            Rrel, Rw1, Rw2, out, nullptr, n);
    }
}